// Round 10
// baseline (116.755 us; speedup 1.0000x reference)
//
#include <hip/hip_runtime.h>

#define NUM_CP 64
#define D_MODEL 128

typedef float f32x4 __attribute__((ext_vector_type(4)));

// Exact algebraic collapse of the reference for t in [0,1]:
//   out[n][d] = B[d] + clip(t[n],0,1) * C[d]
//   B[d] = sum_{i=0}^{62} (1 - i) * cp[i][d]
//   C[d] = -cp[0][d] + sum_{i=1}^{62} cp[i][d]
//
// R10: single-variable A/B vs R9 — PLAIN stores (L2 allocate + writeback)
// on the 1 KB-contiguous store layout. The 6.9 TB/s fill kernel uses plain
// stores; our NT>plain evidence (R5/R6) was measured only on the old
// 2-segment layout. Mechanism under test: NT bypasses L2 write-combining
// and may cap near 5 TB/s; plain full-line wave stores aggregate in L2 and
// write back at controller-friendly burst sizes (fill's 6.9 TB/s path).
__global__ __launch_bounds__(256) void spline_fused(const float* __restrict__ t,
                                                    const float* __restrict__ cp,
                                                    float* __restrict__ out, int n) {
    __shared__ float sbc[2 * D_MODEL];

    const int tid = threadIdx.x;
    if (tid < D_MODEL) {
        float v0 = cp[tid];            // cp[0][d]
        float B = v0, C = -v0;
        for (int i = 1; i < NUM_CP - 1; ++i) {
            float v = cp[i * D_MODEL + tid];
            B = fmaf(1.0f - (float)i, v, B);
            C += v;
        }
        sbc[tid] = B;
        sbc[D_MODEL + tid] = C;
    }
    __syncthreads();

    const int lane = tid & 63;
    const int c    = lane & 31;        // float4 column (0..31) -> dims 4c..4c+3
    const int half = lane >> 5;        // 0: even row of pair, 1: odd row

    const f32x4 b  = reinterpret_cast<const f32x4*>(sbc)[c];
    const f32x4 cv = reinterpret_cast<const f32x4*>(sbc + D_MODEL)[c];

    const int waveGlobal = blockIdx.x * 4 + (tid >> 6);
    const int nWaves     = gridDim.x * 4;
    const int rowStride  = nWaves * 8;
    f32x4* __restrict__ outq = reinterpret_cast<f32x4*>(out);

    int R0 = waveGlobal * 8;
    if (R0 >= n) return;

    bool full = (R0 + 7 < n);
    f32x4 ta, tb;                      // t[R0..R0+3], t[R0+4..R0+7] (broadcast)
    if (full) {
        ta = *reinterpret_cast<const f32x4*>(t + R0);
        tb = *reinterpret_cast<const f32x4*>(t + R0 + 4);
    }

    for (; R0 < n; R0 += rowStride) {
        const int R0n = R0 + rowStride;
        const bool fulln = (R0n + 7 < n);
        f32x4 tan_, tbn;
        if (fulln) {                   // prefetch next iter BEFORE stores
            tan_ = *reinterpret_cast<const f32x4*>(t + R0n);
            tbn  = *reinterpret_cast<const f32x4*>(t + R0n + 4);
        }

        if (full) {
            // this thread's rows: R0 + 2k + half, k = 0..3
            float tv[4];
            tv[0] = half ? ta.y : ta.x;
            tv[1] = half ? ta.w : ta.z;
            tv[2] = half ? tb.y : tb.x;
            tv[3] = half ? tb.w : tb.z;
#pragma unroll
            for (int k = 0; k < 4; ++k) tv[k] = fminf(fmaxf(tv[k], 0.0f), 1.0f);
#pragma unroll
            for (int k = 0; k < 4; ++k) {
                f32x4 o;
                o.x = fmaf(tv[k], cv.x, b.x);
                o.y = fmaf(tv[k], cv.y, b.y);
                o.z = fmaf(tv[k], cv.z, b.z);
                o.w = fmaf(tv[k], cv.w, b.w);
                // rows (R0+2k) and (R0+2k+1): lane l -> base + l*16, 1 KB contiguous
                outq[(R0 + 2 * k + half) * 32 + c] = o;
            }
        } else {
            for (int k = 0; k < 4; ++k) {
                const int r = R0 + 2 * k + half;
                if (r < n) {
                    float tv = fminf(fmaxf(t[r], 0.0f), 1.0f);
                    f32x4 o;
                    o.x = fmaf(tv, cv.x, b.x);
                    o.y = fmaf(tv, cv.y, b.y);
                    o.z = fmaf(tv, cv.z, b.z);
                    o.w = fmaf(tv, cv.w, b.w);
                    outq[r * 32 + c] = o;
                }
            }
        }
        ta = tan_;
        tb = tbn;
        full = fulln;
    }
}

extern "C" void kernel_launch(void* const* d_in, const int* in_sizes, int n_in,
                              void* d_out, int out_size, void* d_ws, size_t ws_size,
                              hipStream_t stream) {
    const float* t  = (const float*)d_in[0];
    const float* cp = (const float*)d_in[1];
    float* out = (float*)d_out;
    const int n = in_sizes[0];

    // 2048 blocks x 256 threads = 8 blocks/CU -> full 32-wave occupancy.
    const int waveTasks  = (n + 7) / 8;          // 8 rows per wave-iter
    const int wantBlocks = (waveTasks + 3) / 4;  // 4 waves per block
    const int blocks = wantBlocks < 2048 ? wantBlocks : 2048;
    spline_fused<<<blocks, 256, 0, stream>>>(t, cp, out, n);
}

// Round 11
// 103.948 us; speedup vs baseline: 1.1232x; 1.1232x over previous
//
#include <hip/hip_runtime.h>

#define NUM_CP 64
#define D_MODEL 128
#define RPW 128   // contiguous rows per wave (64 KB sequential store stream)

typedef float f32x4 __attribute__((ext_vector_type(4)));

// Exact algebraic collapse of the reference for t in [0,1]:
//   out[n][d] = B[d] + clip(t[n],0,1) * C[d]
//   B[d] = sum_{i=0}^{62} (1 - i) * cp[i][d]
//   C[d] = -cp[0][d] + sum_{i=1}^{62} cp[i][d]
//
// R11: single-variable A/B vs R9 — wave-CONTIGUOUS row spans. Each wave owns
// RPW=128 consecutive rows and writes one 64 KB sequential NT stream (16
// iters x 4 KB), instead of 4 KB chunks strided 33 MB apart (R9). Tests the
// last unfalsified difference vs the 6.9 TB/s fill kernel: per-wave
// sequential run length at the memory controllers. NT stores, 1 KB-
// contiguous store layout, t prefetch pipeline, per-block coeff prologue
// all unchanged.
__global__ __launch_bounds__(256) void spline_fused(const float* __restrict__ t,
                                                    const float* __restrict__ cp,
                                                    float* __restrict__ out, int n) {
    __shared__ float sbc[2 * D_MODEL];

    const int tid = threadIdx.x;
    if (tid < D_MODEL) {
        float v0 = cp[tid];            // cp[0][d]
        float B = v0, C = -v0;
        for (int i = 1; i < NUM_CP - 1; ++i) {
            float v = cp[i * D_MODEL + tid];
            B = fmaf(1.0f - (float)i, v, B);
            C += v;
        }
        sbc[tid] = B;
        sbc[D_MODEL + tid] = C;
    }
    __syncthreads();

    const int lane = tid & 63;
    const int c    = lane & 31;        // float4 column (0..31) -> dims 4c..4c+3
    const int half = lane >> 5;        // 0: even row of pair, 1: odd row

    const f32x4 b  = reinterpret_cast<const f32x4*>(sbc)[c];
    const f32x4 cv = reinterpret_cast<const f32x4*>(sbc + D_MODEL)[c];

    const int waveGlobal = blockIdx.x * 4 + (tid >> 6);
    const int base = waveGlobal * RPW;
    if (base >= n) return;
    const int end = min(base + RPW, n);
    f32x4* __restrict__ outq = reinterpret_cast<f32x4*>(out);

    int r0 = base;
    bool full = (r0 + 7 < end);
    f32x4 ta, tb;                      // t[r0..r0+3], t[r0+4..r0+7] (broadcast)
    if (full) {
        ta = *reinterpret_cast<const f32x4*>(t + r0);
        tb = *reinterpret_cast<const f32x4*>(t + r0 + 4);
    }

    for (; r0 < end; r0 += 8) {
        const int r0n = r0 + 8;
        const bool fulln = (r0n + 7 < end);
        f32x4 tan_, tbn;
        if (fulln) {                   // prefetch next iter BEFORE stores
            tan_ = *reinterpret_cast<const f32x4*>(t + r0n);
            tbn  = *reinterpret_cast<const f32x4*>(t + r0n + 4);
        }

        if (full) {
            // this thread's rows: r0 + 2k + half, k = 0..3
            float tv[4];
            tv[0] = half ? ta.y : ta.x;
            tv[1] = half ? ta.w : ta.z;
            tv[2] = half ? tb.y : tb.x;
            tv[3] = half ? tb.w : tb.z;
#pragma unroll
            for (int k = 0; k < 4; ++k) tv[k] = fminf(fmaxf(tv[k], 0.0f), 1.0f);
#pragma unroll
            for (int k = 0; k < 4; ++k) {
                f32x4 o;
                o.x = fmaf(tv[k], cv.x, b.x);
                o.y = fmaf(tv[k], cv.y, b.y);
                o.z = fmaf(tv[k], cv.z, b.z);
                o.w = fmaf(tv[k], cv.w, b.w);
                // rows (r0+2k) and (r0+2k+1): lane l -> base + l*16, 1 KB contiguous
                __builtin_nontemporal_store(o, &outq[(r0 + 2 * k + half) * 32 + c]);
            }
        } else {
            for (int k = 0; k < 4; ++k) {
                const int r = r0 + 2 * k + half;
                if (r < end) {
                    float tv = fminf(fmaxf(t[r], 0.0f), 1.0f);
                    f32x4 o;
                    o.x = fmaf(tv, cv.x, b.x);
                    o.y = fmaf(tv, cv.y, b.y);
                    o.z = fmaf(tv, cv.z, b.z);
                    o.w = fmaf(tv, cv.w, b.w);
                    __builtin_nontemporal_store(o, &outq[r * 32 + c]);
                }
            }
        }
        ta = tan_;
        tb = tbn;
        full = fulln;
    }
}

extern "C" void kernel_launch(void* const* d_in, const int* in_sizes, int n_in,
                              void* d_out, int out_size, void* d_ws, size_t ws_size,
                              hipStream_t stream) {
    const float* t  = (const float*)d_in[0];
    const float* cp = (const float*)d_in[1];
    float* out = (float*)d_out;
    const int n = in_sizes[0];

    // One wave per RPW contiguous rows; 4 waves per block.
    const int waves  = (n + RPW - 1) / RPW;
    const int blocks = (waves + 3) / 4;
    spline_fused<<<blocks, 256, 0, stream>>>(t, cp, out, n);
}